// Round 1
// baseline (13883.070 us; speedup 1.0000x reference)
//
#include <hip/hip_runtime.h>
#include <cstddef>
#include <cstdint>

#define U_DIM 256
#define G_DIM 1024          // 4*U
#define T_DIM 512
#define B_DIM 64
#define TC    128           // timesteps per chunk
#define NCHUNK (T_DIM / TC)

__device__ __forceinline__ float fsig(float x) {
    return 1.0f / (1.0f + __expf(-x));
}

// ---------------------------------------------------------------------------
// GEMM: out[m, :] = A[row(m), :] @ W + bias, for one T-chunk.
// A is [B, T_DIM, 256] fp32; chunk row m = b*TC + tl maps to A row (b*T_DIM + t0 + tl).
// W [256,1024], bias [1024], out [B*TC, 1024] row-major.
// Tile: 64x64, BK=16, 256 threads, 4x4 per thread.
// ---------------------------------------------------------------------------
__global__ __launch_bounds__(256)
void gemm_proj(const float* __restrict__ A, const float* __restrict__ W,
               const float* __restrict__ bias, float* __restrict__ out,
               int t0)
{
    __shared__ float As[16][64];  // [k][m]
    __shared__ float Bs[16][64];  // [k][n]

    const int tid = threadIdx.x;
    const int bm = blockIdx.y * 64;
    const int bn = blockIdx.x * 64;

    // A-load: 64 rows x 16 cols, one float4 per thread
    const int arow = tid >> 2;
    const int acol = (tid & 3) << 2;
    const int m_local = bm + arow;
    const int b  = m_local >> 7;           // / TC (=128)
    const int tl = m_local & (TC - 1);
    const float* arow_ptr = A + (size_t)(b * T_DIM + t0 + tl) * U_DIM;

    // B-load: 16 rows x 64 cols, one float4 per thread
    const int brow = tid >> 4;
    const int bcol = (tid & 15) << 2;

    const int tr = tid >> 4;   // 0..15
    const int tc = tid & 15;   // 0..15

    float acc[4][4] = {};

    for (int k0 = 0; k0 < U_DIM; k0 += 16) {
        const float4 a4 = *(const float4*)(arow_ptr + k0 + acol);
        const float4 b4 = *(const float4*)(W + (size_t)(k0 + brow) * G_DIM + bn + bcol);
        As[acol + 0][arow] = a4.x;
        As[acol + 1][arow] = a4.y;
        As[acol + 2][arow] = a4.z;
        As[acol + 3][arow] = a4.w;
        *(float4*)&Bs[brow][bcol] = b4;
        __syncthreads();
        #pragma unroll
        for (int k = 0; k < 16; ++k) {
            const float4 av = *(const float4*)&As[k][tr << 2];
            const float4 bv = *(const float4*)&Bs[k][tc << 2];
            const float a_[4] = {av.x, av.y, av.z, av.w};
            const float b_[4] = {bv.x, bv.y, bv.z, bv.w};
            #pragma unroll
            for (int i = 0; i < 4; ++i)
                #pragma unroll
                for (int j = 0; j < 4; ++j)
                    acc[i][j] += a_[i] * b_[j];
        }
        __syncthreads();
    }

    const int oc = bn + (tc << 2);
    const float4 bia = *(const float4*)(bias + oc);
    #pragma unroll
    for (int i = 0; i < 4; ++i) {
        const int m = bm + (tr << 2) + i;
        float4 o;
        o.x = acc[i][0] + bia.x;
        o.y = acc[i][1] + bia.y;
        o.z = acc[i][2] + bia.z;
        o.w = acc[i][3] + bia.w;
        *(float4*)(out + (size_t)m * G_DIM + oc) = o;
    }
}

// ---------------------------------------------------------------------------
// Sequential LSTM for one T-chunk. One block per batch row, 1024 threads,
// thread n owns gate-column n. h, c, z in LDS. Carry state in global ws.
// xz: [B*TC, 1024] (precomputed input projection + bias for this chunk)
// Uh: [256, 1024] recurrent weights
// res: optional residual base [B, T_DIM, 256] (added to OUTPUT only)
// outseq: optional [B, T_DIM, 256] output base
// hstate/cstate: [B,256] carry (ignored & zeroed when t0==0)
// ---------------------------------------------------------------------------
__global__ __launch_bounds__(1024)
void lstm_chunk(const float* __restrict__ xz, const float* __restrict__ Uh,
                const float* __restrict__ res, float* __restrict__ outseq,
                float* __restrict__ hstate, float* __restrict__ cstate,
                int t0)
{
    const int b = blockIdx.x;
    const int n = threadIdx.x;

    __shared__ float hsh[U_DIM];
    __shared__ float csh[U_DIM];
    __shared__ float zsh[G_DIM];

    if (n < U_DIM) {
        if (t0 == 0) { hsh[n] = 0.0f; csh[n] = 0.0f; }
        else         { hsh[n] = hstate[b * U_DIM + n]; csh[n] = cstate[b * U_DIM + n]; }
    }
    __syncthreads();

    const float* __restrict__ un = Uh + n;

    for (int tl = 0; tl < TC; ++tl) {
        float acc = xz[(size_t)(b * TC + tl) * G_DIM + n];
        #pragma unroll 4
        for (int k = 0; k < U_DIM; k += 4) {
            const float4 h4 = *(const float4*)&hsh[k];
            acc += h4.x * un[(k + 0) * G_DIM];
            acc += h4.y * un[(k + 1) * G_DIM];
            acc += h4.z * un[(k + 2) * G_DIM];
            acc += h4.w * un[(k + 3) * G_DIM];
        }
        zsh[n] = acc;
        __syncthreads();

        if (n < U_DIM) {
            const float iv = fsig(zsh[n]);
            const float fv = fsig(zsh[n + 256]);
            const float gv = tanhf(zsh[n + 512]);
            const float ov = fsig(zsh[n + 768]);
            const float cc = fv * csh[n] + iv * gv;
            const float hh = ov * tanhf(cc);
            csh[n] = cc;
            hsh[n] = hh;
            if (outseq) {
                const size_t oidx = (size_t)(b * T_DIM + t0 + tl) * U_DIM + n;
                outseq[oidx] = hh + (res ? res[oidx] : 0.0f);
            }
        }
        __syncthreads();
    }

    if (n < U_DIM) {
        hstate[b * U_DIM + n] = hsh[n];
        cstate[b * U_DIM + n] = csh[n];
    }
}

// ---------------------------------------------------------------------------
// Final: y[b,o] = sum_j (h1[b,j] + h2[b, j%256]) * Wd[j,o] + bd[o]
// One block per batch row; 256 threads grid-stride over j=0..131071.
// ---------------------------------------------------------------------------
__global__ __launch_bounds__(256)
void final_proj(const float* __restrict__ h1, const float* __restrict__ h2,
                const float* __restrict__ Wd, const float* __restrict__ bd,
                float* __restrict__ y)
{
    const int b = blockIdx.x;
    const int tid = threadIdx.x;
    const int JTOT = T_DIM * U_DIM;   // 131072

    float a0 = 0.f, a1 = 0.f, a2 = 0.f, a3 = 0.f;
    const float* hb = h1 + (size_t)b * JTOT;
    const float* h2b = h2 + (size_t)b * U_DIM;

    for (int j = tid; j < JTOT; j += 256) {
        const float v = hb[j] + h2b[j & (U_DIM - 1)];
        const float4 w = *(const float4*)&Wd[(size_t)j * 4];
        a0 += v * w.x;
        a1 += v * w.y;
        a2 += v * w.z;
        a3 += v * w.w;
    }

    __shared__ float red[256][4];
    red[tid][0] = a0; red[tid][1] = a1; red[tid][2] = a2; red[tid][3] = a3;
    __syncthreads();
    for (int s = 128; s > 0; s >>= 1) {
        if (tid < s) {
            #pragma unroll
            for (int o = 0; o < 4; ++o) red[tid][o] += red[tid + s][o];
        }
        __syncthreads();
    }
    if (tid < 4) y[b * 4 + tid] = red[0][tid] + bd[tid];
}

// ---------------------------------------------------------------------------
extern "C" void kernel_launch(void* const* d_in, const int* in_sizes, int n_in,
                              void* d_out, int out_size, void* d_ws, size_t ws_size,
                              hipStream_t stream)
{
    (void)in_sizes; (void)n_in; (void)out_size; (void)ws_size;

    const float* x  = (const float*)d_in[0];
    const float* Wr = (const float*)d_in[1];
    const float* Ur = (const float*)d_in[2];
    const float* br = (const float*)d_in[3];
    const float* Wn = (const float*)d_in[4];
    const float* Un = (const float*)d_in[5];
    const float* bn = (const float*)d_in[6];
    const float* Wd = (const float*)d_in[7];
    const float* bd = (const float*)d_in[8];
    float* y = (float*)d_out;

    float* ws = (float*)d_ws;
    const size_t CHUNK_ELEMS = (size_t)B_DIM * TC * G_DIM;      // 8,388,608
    const size_t SEQ_ELEMS   = (size_t)B_DIM * T_DIM * U_DIM;   // 8,388,608
    float* xzbuf = ws;
    float* h0    = xzbuf + CHUNK_ELEMS;
    float* h1    = h0 + SEQ_ELEMS;
    float* hs    = h1 + SEQ_ELEMS;
    float* cs    = hs + (size_t)B_DIM * U_DIM;
    // total ws use: (3*8388608 + 2*16384) * 4 B  ~= 96.1 MiB

    dim3 ggrid(G_DIM / 64, (B_DIM * TC) / 64);   // (16, 128)

    // ---- layer 0: shared LSTM on x, no residual, outputs h0 ----
    for (int ch = 0; ch < NCHUNK; ++ch) {
        const int t0 = ch * TC;
        gemm_proj<<<ggrid, 256, 0, stream>>>(x, Wr, br, xzbuf, t0);
        lstm_chunk<<<B_DIM, 1024, 0, stream>>>(xzbuf, Ur, nullptr, h0, hs, cs, t0);
    }
    // ---- layer 1: same shared weights on h0, residual add, outputs h1 ----
    for (int ch = 0; ch < NCHUNK; ++ch) {
        const int t0 = ch * TC;
        gemm_proj<<<ggrid, 256, 0, stream>>>(h0, Wr, br, xzbuf, t0);
        lstm_chunk<<<B_DIM, 1024, 0, stream>>>(xzbuf, Ur, h0, h1, hs, cs, t0);
    }
    // ---- layer 2: Wn/Un/bn on h1, keep only last hidden state (in hs) ----
    for (int ch = 0; ch < NCHUNK; ++ch) {
        const int t0 = ch * TC;
        gemm_proj<<<ggrid, 256, 0, stream>>>(h1, Wn, bn, xzbuf, t0);
        lstm_chunk<<<B_DIM, 1024, 0, stream>>>(xzbuf, Un, nullptr, nullptr, hs, cs, t0);
    }
    // ---- final projection ----
    final_proj<<<B_DIM, 256, 0, stream>>>(h1, hs, Wd, bd, y);
}